// Round 1
// baseline (2471.415 us; speedup 1.0000x reference)
//
#include <hip/hip_runtime.h>
#include <math.h>

#define DIM   1024
#define HEADS 16
#define DH    64
#define ROT   128
#define BATCH 2
#define SEQ   2048
#define ROWS  (BATCH*SEQ)        // 4096
#define PCOLS (DIM + 2*DH)       // 1152 = [q(1024) | k(64) | v(64)] per side

// ---------------------------------------------------------------------------
// GEMM: P[side][row][j] = In_side[row,:] . W_side[j,:]   (NT gemm, fp32)
// jt 0..7 -> Wq rows jt*128..+127 ; jt==8 -> Wkv rows 0..127
// 128x128 block tile, 256 threads, 8x8 microtile, K-tile 16.
// ---------------------------------------------------------------------------
__global__ __launch_bounds__(256) void gemm_kernel(
    const float* __restrict__ x, const float* __restrict__ a,
    const float* __restrict__ Wq_x, const float* __restrict__ Wkv_x,
    const float* __restrict__ Wq_a, const float* __restrict__ Wkv_a,
    float* __restrict__ P)
{
    const int mt   = blockIdx.x;   // 0..31
    const int jt   = blockIdx.y;   // 0..8
    const int side = blockIdx.z;   // 0=x side, 1=a side
    const float* __restrict__ X = side ? a : x;
    const float* __restrict__ W;
    if (jt < 8) W = (side ? Wq_a : Wq_x) + (size_t)(jt * 128) * DIM;
    else        W = (side ? Wkv_a : Wkv_x);
    float* __restrict__ Pp = P + (size_t)side * ROWS * PCOLS;

    __shared__ float As[16][132];   // [k][m], +4 pad keeps float4 alignment, kills conflicts
    __shared__ float Bs[16][132];   // [k][j]
    const int tid = threadIdx.x;
    const int tx = tid & 15, ty = tid >> 4;
    const int m0 = mt * 128;

    float acc[8][8];
    #pragma unroll
    for (int i = 0; i < 8; i++)
        #pragma unroll
        for (int j = 0; j < 8; j++) acc[i][j] = 0.f;

    for (int k0 = 0; k0 < DIM; k0 += 16) {
        #pragma unroll
        for (int it = 0; it < 2; it++) {
            int idx = tid + it * 256;
            int r = idx >> 2, c = (idx & 3) * 4;
            float4 va = *(const float4*)(X + (size_t)(m0 + r) * DIM + k0 + c);
            As[c + 0][r] = va.x; As[c + 1][r] = va.y; As[c + 2][r] = va.z; As[c + 3][r] = va.w;
            float4 vb = *(const float4*)(W + (size_t)r * DIM + k0 + c);
            Bs[c + 0][r] = vb.x; Bs[c + 1][r] = vb.y; Bs[c + 2][r] = vb.z; Bs[c + 3][r] = vb.w;
        }
        __syncthreads();
        #pragma unroll
        for (int kk = 0; kk < 16; kk++) {
            float av[8], bv[8];
            *(float4*)&av[0] = *(const float4*)&As[kk][ty * 8];
            *(float4*)&av[4] = *(const float4*)&As[kk][ty * 8 + 4];
            *(float4*)&bv[0] = *(const float4*)&Bs[kk][tx * 8];
            *(float4*)&bv[4] = *(const float4*)&Bs[kk][tx * 8 + 4];
            #pragma unroll
            for (int i = 0; i < 8; i++)
                #pragma unroll
                for (int j = 0; j < 8; j++) acc[i][j] = fmaf(av[i], bv[j], acc[i][j]);
        }
        __syncthreads();
    }
    #pragma unroll
    for (int i = 0; i < 8; i++) {
        float* pp = Pp + (size_t)(m0 + ty * 8 + i) * PCOLS + jt * 128 + tx * 8;
        *(float4*)(pp)     = make_float4(acc[i][0], acc[i][1], acc[i][2], acc[i][3]);
        *(float4*)(pp + 4) = make_float4(acc[i][4], acc[i][5], acc[i][6], acc[i][7]);
    }
}

// ---------------------------------------------------------------------------
// Fuse: l2norm + scale + concat + rotary -> qbuf[b][h][n][128], kbuf/vbuf[b][n][128]
// one block per (b,pos) row; 256 threads = 16 heads x 16 lanes (4 dims each)
// rotary pairs (d, d+64) share angle theta = pos * 10000^(-d/64)
// ---------------------------------------------------------------------------
__global__ __launch_bounds__(256) void fuse_kernel(
    const float* __restrict__ P,
    const float* __restrict__ qx_scale, const float* __restrict__ qa_scale,
    const float* __restrict__ kx_scale, const float* __restrict__ ka_scale,
    float* __restrict__ qbuf, float* __restrict__ kbuf, float* __restrict__ vbuf)
{
    const int row = blockIdx.x;            // b*SEQ + pos
    const int b = row >> 11, pos = row & 2047;
    const float* __restrict__ Px = P + (size_t)row * PCOLS;
    const float* __restrict__ Pa = P + (size_t)ROWS * PCOLS + (size_t)row * PCOLS;
    const int tid = threadIdx.x;
    const int h = tid >> 4, i = tid & 15;
    const float fpos = (float)pos;
    const float LN1E4_64 = 0.14391156831213f;   // ln(10000)/64

    // ---- Q ----
    float4 xv = *(const float4*)(Px + h * DH + i * 4);
    float4 av = *(const float4*)(Pa + h * DH + i * 4);
    float ssx = xv.x*xv.x + xv.y*xv.y + xv.z*xv.z + xv.w*xv.w;
    float ssa = av.x*av.x + av.y*av.y + av.z*av.z + av.w*av.w;
    #pragma unroll
    for (int off = 1; off < 16; off <<= 1) {
        ssx += __shfl_xor(ssx, off, 16);
        ssa += __shfl_xor(ssa, off, 16);
    }
    float inx = 1.0f / fmaxf(sqrtf(ssx), 1e-12f);
    float ina = 1.0f / fmaxf(sqrtf(ssa), 1e-12f);
    float xr[4] = {xv.x, xv.y, xv.z, xv.w};
    float ar[4] = {av.x, av.y, av.z, av.w};
    float qlo[4], qhi[4];
    #pragma unroll
    for (int j = 0; j < 4; j++) {
        int jd = i * 4 + j;
        float qx = xr[j] * inx * qx_scale[h * DH + jd];
        float qa = ar[j] * ina * qa_scale[h * DH + jd];
        float th = fpos * expf(-LN1E4_64 * (float)jd);
        float sn, cs; sincosf(th, &sn, &cs);
        qlo[j] = qx * cs - qa * sn;
        qhi[j] = qa * cs + qx * sn;
    }
    float* qp = qbuf + (((size_t)(b * HEADS + h)) * SEQ + pos) * ROT;
    *(float4*)(qp + i * 4)      = make_float4(qlo[0], qlo[1], qlo[2], qlo[3]);
    *(float4*)(qp + DH + i * 4) = make_float4(qhi[0], qhi[1], qhi[2], qhi[3]);

    // ---- K ---- (threads 0..15, one 64-dim head each side)
    if (tid < 16) {
        float4 kx4 = *(const float4*)(Px + DIM + tid * 4);
        float4 ka4 = *(const float4*)(Pa + DIM + tid * 4);
        float sx = kx4.x*kx4.x + kx4.y*kx4.y + kx4.z*kx4.z + kx4.w*kx4.w;
        float sa = ka4.x*ka4.x + ka4.y*ka4.y + ka4.z*ka4.z + ka4.w*ka4.w;
        #pragma unroll
        for (int off = 1; off < 16; off <<= 1) {
            sx += __shfl_xor(sx, off, 16);
            sa += __shfl_xor(sa, off, 16);
        }
        float ikx = 1.0f / fmaxf(sqrtf(sx), 1e-12f);
        float ika = 1.0f / fmaxf(sqrtf(sa), 1e-12f);
        float kxr[4] = {kx4.x, kx4.y, kx4.z, kx4.w};
        float kar[4] = {ka4.x, ka4.y, ka4.z, ka4.w};
        float klo[4], khi[4];
        #pragma unroll
        for (int j = 0; j < 4; j++) {
            int jd = tid * 4 + j;
            float kx = kxr[j] * ikx * kx_scale[jd];
            float ka = kar[j] * ika * ka_scale[jd];
            float th = fpos * expf(-LN1E4_64 * (float)jd);
            float sn, cs; sincosf(th, &sn, &cs);
            klo[j] = kx * cs - ka * sn;
            khi[j] = ka * cs + kx * sn;
        }
        float* kp = kbuf + ((size_t)b * SEQ + pos) * ROT;
        *(float4*)(kp + tid * 4)      = make_float4(klo[0], klo[1], klo[2], klo[3]);
        *(float4*)(kp + DH + tid * 4) = make_float4(khi[0], khi[1], khi[2], khi[3]);
    }
    // ---- V ---- (threads 64..95, plain copy)
    if (tid >= 64 && tid < 96) {
        int iv = tid - 64;
        float* vp = vbuf + ((size_t)b * SEQ + pos) * ROT;
        if (iv < 16) *(float4*)(vp + iv * 4)             = *(const float4*)(Px + DIM + DH + iv * 4);
        else         *(float4*)(vp + DH + (iv - 16) * 4) = *(const float4*)(Pa + DIM + DH + (iv - 16) * 4);
    }
}

// ---------------------------------------------------------------------------
// Flash attention (fp32): block = (b, h, 64-query tile), 256 threads.
// lane -> part = lane&7 (16 dims), rowg = lane>>3; each thread owns 2 q rows.
// K/V tiles of 32 staged in LDS; online softmax; 8-lane shfl reduce for dots.
// ---------------------------------------------------------------------------
__global__ __launch_bounds__(256) void attn_kernel(
    const float* __restrict__ qbuf, const float* __restrict__ kbuf,
    const float* __restrict__ vbuf, float* __restrict__ out)
{
    const int qb = blockIdx.x;   // 0..31
    const int h  = blockIdx.y;   // 0..15
    const int b  = blockIdx.z;   // 0..1
    __shared__ float kt[32 * ROT];
    __shared__ float vt[32 * ROT];
    const int tid  = threadIdx.x;
    const int lane = tid & 63, wave = tid >> 6;
    const int part = lane & 7, rowg = lane >> 3;
    const int dbase = part * 16;
    const float scale = 0.088388347648318447f;   // 1/sqrt(128)

    float qf[2][16], oacc[2][16];
    float mr[2] = {-INFINITY, -INFINITY};
    float lr[2] = {0.f, 0.f};
    #pragma unroll
    for (int r = 0; r < 2; r++) {
        const int qg = qb * 64 + wave * 8 + rowg + r * 32;
        const float* qp = qbuf + (((size_t)(b * HEADS + h)) * SEQ + qg) * ROT + dbase;
        #pragma unroll
        for (int j = 0; j < 16; j += 4) {
            float4 v4 = *(const float4*)(qp + j);
            qf[r][j] = v4.x * scale; qf[r][j+1] = v4.y * scale;
            qf[r][j+2] = v4.z * scale; qf[r][j+3] = v4.w * scale;
        }
        #pragma unroll
        for (int j = 0; j < 16; j++) oacc[r][j] = 0.f;
    }
    const float* kb = kbuf + (size_t)b * SEQ * ROT;
    const float* vb = vbuf + (size_t)b * SEQ * ROT;

    for (int t = 0; t < SEQ / 32; t++) {
        #pragma unroll
        for (int it = 0; it < 4; it++) {
            int idx = tid + it * 256;
            int rr = idx >> 5, c = (idx & 31) * 4;
            *(float4*)&kt[rr * ROT + c] = *(const float4*)(kb + (size_t)(t * 32 + rr) * ROT + c);
            *(float4*)&vt[rr * ROT + c] = *(const float4*)(vb + (size_t)(t * 32 + rr) * ROT + c);
        }
        __syncthreads();

        float s[2][32];
        #pragma unroll
        for (int kk = 0; kk < 32; kk++) {
            float kv[16];
            *(float4*)&kv[0]  = *(const float4*)&kt[kk * ROT + dbase];
            *(float4*)&kv[4]  = *(const float4*)&kt[kk * ROT + dbase + 4];
            *(float4*)&kv[8]  = *(const float4*)&kt[kk * ROT + dbase + 8];
            *(float4*)&kv[12] = *(const float4*)&kt[kk * ROT + dbase + 12];
            float p0a = 0.f, p0b = 0.f, p1a = 0.f, p1b = 0.f;
            #pragma unroll
            for (int j = 0; j < 8; j++) {
                p0a = fmaf(qf[0][j],     kv[j],     p0a);
                p0b = fmaf(qf[0][j + 8], kv[j + 8], p0b);
                p1a = fmaf(qf[1][j],     kv[j],     p1a);
                p1b = fmaf(qf[1][j + 8], kv[j + 8], p1b);
            }
            float p0 = p0a + p0b, p1 = p1a + p1b;
            #pragma unroll
            for (int off = 1; off < 8; off <<= 1) {
                p0 += __shfl_xor(p0, off, 8);
                p1 += __shfl_xor(p1, off, 8);
            }
            s[0][kk] = p0; s[1][kk] = p1;
        }

        #pragma unroll
        for (int r = 0; r < 2; r++) {
            float tmax = s[r][0];
            #pragma unroll
            for (int kk = 1; kk < 32; kk++) tmax = fmaxf(tmax, s[r][kk]);
            float mnew  = fmaxf(mr[r], tmax);
            float alpha = __expf(mr[r] - mnew);
            mr[r] = mnew;
            float lsum = 0.f;
            #pragma unroll
            for (int kk = 0; kk < 32; kk++) {
                float p = __expf(s[r][kk] - mnew);
                s[r][kk] = p; lsum += p;
            }
            lr[r] = lr[r] * alpha + lsum;
            #pragma unroll
            for (int j = 0; j < 16; j++) oacc[r][j] *= alpha;
        }

        #pragma unroll
        for (int kk = 0; kk < 32; kk++) {
            float vv[16];
            *(float4*)&vv[0]  = *(const float4*)&vt[kk * ROT + dbase];
            *(float4*)&vv[4]  = *(const float4*)&vt[kk * ROT + dbase + 4];
            *(float4*)&vv[8]  = *(const float4*)&vt[kk * ROT + dbase + 8];
            *(float4*)&vv[12] = *(const float4*)&vt[kk * ROT + dbase + 12];
            #pragma unroll
            for (int j = 0; j < 16; j++) {
                oacc[0][j] = fmaf(s[0][kk], vv[j], oacc[0][j]);
                oacc[1][j] = fmaf(s[1][kk], vv[j], oacc[1][j]);
            }
        }
        __syncthreads();
    }

    #pragma unroll
    for (int r = 0; r < 2; r++) {
        const int qg = qb * 64 + wave * 8 + rowg + r * 32;
        float inv = 1.0f / lr[r];
        float* op = out + ((size_t)(b * SEQ + qg)) * (HEADS * ROT) + h * ROT + dbase;
        #pragma unroll
        for (int j = 0; j < 16; j += 4)
            *(float4*)(op + j) = make_float4(oacc[r][j] * inv, oacc[r][j+1] * inv,
                                             oacc[r][j+2] * inv, oacc[r][j+3] * inv);
    }
}

// ---------------------------------------------------------------------------
extern "C" void kernel_launch(void* const* d_in, const int* in_sizes, int n_in,
                              void* d_out, int out_size, void* d_ws, size_t ws_size,
                              hipStream_t stream) {
    (void)in_sizes; (void)n_in; (void)out_size; (void)ws_size;
    const float* x        = (const float*)d_in[0];
    const float* a        = (const float*)d_in[1];
    const float* Wq_x     = (const float*)d_in[2];
    const float* Wkv_x    = (const float*)d_in[3];
    const float* Wq_a     = (const float*)d_in[4];
    const float* Wkv_a    = (const float*)d_in[5];
    const float* qx_scale = (const float*)d_in[6];
    const float* qa_scale = (const float*)d_in[7];
    const float* kx_scale = (const float*)d_in[8];
    const float* ka_scale = (const float*)d_in[9];
    float* out = (float*)d_out;

    // workspace: P (2*4096*1152) + qbuf (2*16*2048*128) + kbuf/vbuf (2*2048*128 each)
    // = 18,874,368 floats = 75.5 MB
    float* P    = (float*)d_ws;
    float* qbuf = P + (size_t)2 * ROWS * PCOLS;
    float* kbuf = qbuf + (size_t)BATCH * HEADS * SEQ * ROT;
    float* vbuf = kbuf + (size_t)BATCH * SEQ * ROT;

    gemm_kernel<<<dim3(32, 9, 2), 256, 0, stream>>>(x, a, Wq_x, Wkv_x, Wq_a, Wkv_a, P);
    fuse_kernel<<<dim3(ROWS), 256, 0, stream>>>(P, qx_scale, qa_scale, kx_scale, ka_scale,
                                                qbuf, kbuf, vbuf);
    attn_kernel<<<dim3(SEQ / 64, HEADS, BATCH), 256, 0, stream>>>(qbuf, kbuf, vbuf, out);
}

// Round 2
// 470.275 us; speedup vs baseline: 5.2553x; 5.2553x over previous
//
#include <hip/hip_runtime.h>
#include <math.h>

#define DIM   1024
#define HEADS 16
#define DH    64
#define ROT   128
#define BATCH 2
#define SEQ   2048
#define ROWS  (BATCH*SEQ)        // 4096
#define PCOLS (DIM + 2*DH)       // 1152 = [q(1024) | k(64) | v(64)] per side
#define ASCALE 0.08838834764831845f   // 1/sqrt(128), folded into qbuf

typedef short bf16x8 __attribute__((ext_vector_type(8)));
typedef float f32x16 __attribute__((ext_vector_type(16)));

static __device__ __forceinline__ unsigned short f2bf(float f) {
    union { float f; unsigned u; } v; v.f = f;
    unsigned r = v.u + 0x7fffu + ((v.u >> 16) & 1u);   // RNE (no NaN inputs here)
    return (unsigned short)(r >> 16);
}

// ---------------------------------------------------------------------------
// GEMM (fp32 vector, unchanged this round): P[side][row][j] = In[row,:].W[j,:]
// ---------------------------------------------------------------------------
__global__ __launch_bounds__(256) void gemm_kernel(
    const float* __restrict__ x, const float* __restrict__ a,
    const float* __restrict__ Wq_x, const float* __restrict__ Wkv_x,
    const float* __restrict__ Wq_a, const float* __restrict__ Wkv_a,
    float* __restrict__ P)
{
    const int mt   = blockIdx.x;
    const int jt   = blockIdx.y;
    const int side = blockIdx.z;
    const float* __restrict__ X = side ? a : x;
    const float* __restrict__ W;
    if (jt < 8) W = (side ? Wq_a : Wq_x) + (size_t)(jt * 128) * DIM;
    else        W = (side ? Wkv_a : Wkv_x);
    float* __restrict__ Pp = P + (size_t)side * ROWS * PCOLS;

    __shared__ float As[16][132];
    __shared__ float Bs[16][132];
    const int tid = threadIdx.x;
    const int tx = tid & 15, ty = tid >> 4;
    const int m0 = mt * 128;

    float acc[8][8];
    #pragma unroll
    for (int i = 0; i < 8; i++)
        #pragma unroll
        for (int j = 0; j < 8; j++) acc[i][j] = 0.f;

    for (int k0 = 0; k0 < DIM; k0 += 16) {
        #pragma unroll
        for (int it = 0; it < 2; it++) {
            int idx = tid + it * 256;
            int r = idx >> 2, c = (idx & 3) * 4;
            float4 va = *(const float4*)(X + (size_t)(m0 + r) * DIM + k0 + c);
            As[c + 0][r] = va.x; As[c + 1][r] = va.y; As[c + 2][r] = va.z; As[c + 3][r] = va.w;
            float4 vb = *(const float4*)(W + (size_t)r * DIM + k0 + c);
            Bs[c + 0][r] = vb.x; Bs[c + 1][r] = vb.y; Bs[c + 2][r] = vb.z; Bs[c + 3][r] = vb.w;
        }
        __syncthreads();
        #pragma unroll
        for (int kk = 0; kk < 16; kk++) {
            float av[8], bv[8];
            *(float4*)&av[0] = *(const float4*)&As[kk][ty * 8];
            *(float4*)&av[4] = *(const float4*)&As[kk][ty * 8 + 4];
            *(float4*)&bv[0] = *(const float4*)&Bs[kk][tx * 8];
            *(float4*)&bv[4] = *(const float4*)&Bs[kk][tx * 8 + 4];
            #pragma unroll
            for (int i = 0; i < 8; i++)
                #pragma unroll
                for (int j = 0; j < 8; j++) acc[i][j] = fmaf(av[i], bv[j], acc[i][j]);
        }
        __syncthreads();
    }
    #pragma unroll
    for (int i = 0; i < 8; i++) {
        float* pp = Pp + (size_t)(m0 + ty * 8 + i) * PCOLS + jt * 128 + tx * 8;
        *(float4*)(pp)     = make_float4(acc[i][0], acc[i][1], acc[i][2], acc[i][3]);
        *(float4*)(pp + 4) = make_float4(acc[i][4], acc[i][5], acc[i][6], acc[i][7]);
    }
}

// ---------------------------------------------------------------------------
// Fuse: l2norm + scale + concat + rotary.
// Outputs (bf16): qbuf[b][h][n][128] (pre-scaled by 1/sqrt(128)),
//                 kbuf[b][n][128], vbufT[b][128][n] (transposed for attn)
// ---------------------------------------------------------------------------
__global__ __launch_bounds__(256) void fuse_kernel(
    const float* __restrict__ P,
    const float* __restrict__ qx_scale, const float* __restrict__ qa_scale,
    const float* __restrict__ kx_scale, const float* __restrict__ ka_scale,
    unsigned short* __restrict__ qbuf, unsigned short* __restrict__ kbuf,
    unsigned short* __restrict__ vbufT)
{
    const int row = blockIdx.x;            // b*SEQ + pos
    const int b = row >> 11, pos = row & 2047;
    const float* __restrict__ Px = P + (size_t)row * PCOLS;
    const float* __restrict__ Pa = P + (size_t)ROWS * PCOLS + (size_t)row * PCOLS;
    const int tid = threadIdx.x;
    const int h = tid >> 4, i = tid & 15;
    const float fpos = (float)pos;
    const float LN1E4_64 = 0.14391156831213f;   // ln(10000)/64

    // ---- Q ----
    float4 xv = *(const float4*)(Px + h * DH + i * 4);
    float4 av = *(const float4*)(Pa + h * DH + i * 4);
    float ssx = xv.x*xv.x + xv.y*xv.y + xv.z*xv.z + xv.w*xv.w;
    float ssa = av.x*av.x + av.y*av.y + av.z*av.z + av.w*av.w;
    #pragma unroll
    for (int off = 1; off < 16; off <<= 1) {
        ssx += __shfl_xor(ssx, off, 16);
        ssa += __shfl_xor(ssa, off, 16);
    }
    float inx = 1.0f / fmaxf(sqrtf(ssx), 1e-12f);
    float ina = 1.0f / fmaxf(sqrtf(ssa), 1e-12f);
    float xr[4] = {xv.x, xv.y, xv.z, xv.w};
    float ar[4] = {av.x, av.y, av.z, av.w};
    unsigned short qlo[4], qhi[4];
    #pragma unroll
    for (int j = 0; j < 4; j++) {
        int jd = i * 4 + j;
        float qx = xr[j] * inx * qx_scale[h * DH + jd];
        float qa = ar[j] * ina * qa_scale[h * DH + jd];
        float th = fpos * expf(-LN1E4_64 * (float)jd);
        float sn, cs; sincosf(th, &sn, &cs);
        qlo[j] = f2bf((qx * cs - qa * sn) * ASCALE);
        qhi[j] = f2bf((qa * cs + qx * sn) * ASCALE);
    }
    unsigned short* qp = qbuf + (((size_t)(b * HEADS + h)) * SEQ + pos) * ROT;
    *(ushort4*)(qp + i * 4)      = make_ushort4(qlo[0], qlo[1], qlo[2], qlo[3]);
    *(ushort4*)(qp + DH + i * 4) = make_ushort4(qhi[0], qhi[1], qhi[2], qhi[3]);

    // ---- K ----
    if (tid < 16) {
        float4 kx4 = *(const float4*)(Px + DIM + tid * 4);
        float4 ka4 = *(const float4*)(Pa + DIM + tid * 4);
        float sx = kx4.x*kx4.x + kx4.y*kx4.y + kx4.z*kx4.z + kx4.w*kx4.w;
        float sa = ka4.x*ka4.x + ka4.y*ka4.y + ka4.z*ka4.z + ka4.w*ka4.w;
        #pragma unroll
        for (int off = 1; off < 16; off <<= 1) {
            sx += __shfl_xor(sx, off, 16);
            sa += __shfl_xor(sa, off, 16);
        }
        float ikx = 1.0f / fmaxf(sqrtf(sx), 1e-12f);
        float ika = 1.0f / fmaxf(sqrtf(sa), 1e-12f);
        float kxr[4] = {kx4.x, kx4.y, kx4.z, kx4.w};
        float kar[4] = {ka4.x, ka4.y, ka4.z, ka4.w};
        unsigned short klo[4], khi[4];
        #pragma unroll
        for (int j = 0; j < 4; j++) {
            int jd = tid * 4 + j;
            float kx = kxr[j] * ikx * kx_scale[jd];
            float ka = kar[j] * ika * ka_scale[jd];
            float th = fpos * expf(-LN1E4_64 * (float)jd);
            float sn, cs; sincosf(th, &sn, &cs);
            klo[j] = f2bf(kx * cs - ka * sn);
            khi[j] = f2bf(ka * cs + kx * sn);
        }
        unsigned short* kp = kbuf + ((size_t)b * SEQ + pos) * ROT;
        *(ushort4*)(kp + tid * 4)      = make_ushort4(klo[0], klo[1], klo[2], klo[3]);
        *(ushort4*)(kp + DH + tid * 4) = make_ushort4(khi[0], khi[1], khi[2], khi[3]);
    }
    // ---- V (transposed store, bf16) ----
    if (tid >= 64 && tid < 96) {
        int iv = tid - 64;
        unsigned short* vT = vbufT + (size_t)b * ROT * SEQ + pos;
        if (iv < 16) {
            float4 v4 = *(const float4*)(Px + DIM + DH + iv * 4);
            int d = iv * 4;
            vT[(size_t)(d + 0) * SEQ] = f2bf(v4.x);
            vT[(size_t)(d + 1) * SEQ] = f2bf(v4.y);
            vT[(size_t)(d + 2) * SEQ] = f2bf(v4.z);
            vT[(size_t)(d + 3) * SEQ] = f2bf(v4.w);
        } else {
            float4 v4 = *(const float4*)(Pa + DIM + DH + (iv - 16) * 4);
            int d = DH + (iv - 16) * 4;
            vT[(size_t)(d + 0) * SEQ] = f2bf(v4.x);
            vT[(size_t)(d + 1) * SEQ] = f2bf(v4.y);
            vT[(size_t)(d + 2) * SEQ] = f2bf(v4.z);
            vT[(size_t)(d + 3) * SEQ] = f2bf(v4.w);
        }
    }
}

// ---------------------------------------------------------------------------
// MFMA flash attention (bf16, 32x32x16):
//   block = 4 waves x 32 q-rows = 128 q-rows per (b,h); grid (16,16,2).
//   Per 64-key tile: stage K[64][128] + V^T[128][64] in LDS (XOR-granule
//   swizzle, conflict-free b128 reads).
//   S^T = K @ Q^T via mfma(A=K-frag from LDS, B=Q-frag resident in regs).
//   No max-tracking softmax (|s| <= 0.18 by construction): p = exp(s).
//   P A-fragment built from S^T C-layout via 4 shfl_xor(32) per 16-key window.
//   O += P @ V^T-frag; divide by row-sum at the end.
// ---------------------------------------------------------------------------
__global__ __launch_bounds__(256, 2) void attn_kernel(
    const unsigned short* __restrict__ qbuf,
    const unsigned short* __restrict__ kbuf,
    const unsigned short* __restrict__ vbufT,
    float* __restrict__ out)
{
    const int qb = blockIdx.x, h = blockIdx.y, b = blockIdx.z;
    __shared__ __align__(16) unsigned short Ks[64 * 128];
    __shared__ __align__(16) unsigned short Vs[128 * 64];
    const int tid  = threadIdx.x;
    const int wave = tid >> 6, lane = tid & 63;
    const int m = lane & 31, hl = lane >> 5;
    const int q0 = qb * 128 + wave * 32;

    // Q resident: B-frag chunk c covers d = c*16 + hl*8 + j
    bf16x8 qf[8];
    {
        const unsigned short* qp = qbuf + (((size_t)(b * HEADS + h)) * SEQ + q0 + m) * ROT + hl * 8;
        #pragma unroll
        for (int c = 0; c < 8; c++) qf[c] = *(const bf16x8*)(qp + c * 16);
    }

    f32x16 oacc[4];
    #pragma unroll
    for (int dt = 0; dt < 4; dt++) oacc[dt] = 0.0f;
    float lsum = 0.f;

    const unsigned short* kb_ = kbuf  + (size_t)b * SEQ * ROT;
    const unsigned short* vb_ = vbufT + (size_t)b * ROT * SEQ;

    for (int t = 0; t < SEQ / 64; t++) {
        __syncthreads();
        #pragma unroll
        for (int i = 0; i < 4; i++) {
            int fg = i * 256 + tid;
            int row = fg >> 4, gi = fg & 15;            // K: 64 rows x 16 granules
            uint4 val = *(const uint4*)(kb_ + (size_t)(t * 64 + row) * ROT + gi * 8);
            *(uint4*)&Ks[row * 128 + ((gi ^ (row & 15)) << 3)] = val;
            int rv = fg >> 3, gv = fg & 7;              // V^T: 128 rows x 8 granules
            uint4 vv = *(const uint4*)(vb_ + (size_t)rv * SEQ + t * 64 + gv * 8);
            *(uint4*)&Vs[rv * 64 + ((gv ^ (rv & 7)) << 3)] = vv;
        }
        __syncthreads();

        #pragma unroll
        for (int kg = 0; kg < 2; kg++) {
            // S^T tile: 32 keys x 32 qrows
            f32x16 st = 0.0f;
            #pragma unroll
            for (int c = 0; c < 8; c++) {
                bf16x8 af = *(const bf16x8*)&Ks[(kg * 32 + m) * 128 + (((2 * c + hl) ^ (m & 15)) << 3)];
                st = __builtin_amdgcn_mfma_f32_32x32x16_bf16(af, qf[c], st, 0, 0, 0);
            }
            float p[16];
            #pragma unroll
            for (int r = 0; r < 16; r++) { p[r] = __expf(st[r]); lsum += p[r]; }

            // PV over two 16-key windows
            #pragma unroll
            for (int w = 0; w < 2; w++) {
                float pj[8];
                #pragma unroll
                for (int tq = 0; tq < 4; tq++) {
                    float send = hl ? p[8 * w + tq]     : p[8 * w + 4 + tq];
                    float own  = hl ? p[8 * w + 4 + tq] : p[8 * w + tq];
                    float recv = __shfl_xor(send, 32);
                    pj[tq]     = hl ? recv : own;
                    pj[4 + tq] = hl ? own  : recv;
                }
                bf16x8 aP;
                #pragma unroll
                for (int j = 0; j < 8; j++) aP[j] = (short)f2bf(pj[j]);
                #pragma unroll
                for (int dt = 0; dt < 4; dt++) {
                    bf16x8 vf = *(const bf16x8*)&Vs[(dt * 32 + m) * 64 +
                                                    (((kg * 4 + w * 2 + hl) ^ (m & 7)) << 3)];
                    oacc[dt] = __builtin_amdgcn_mfma_f32_32x32x16_bf16(aP, vf, oacc[dt], 0, 0, 0);
                }
            }
        }
    }

    lsum += __shfl_xor(lsum, 32);    // add other half's keys
    float* ob = out + ((size_t)(b * SEQ + q0)) * (HEADS * ROT) + h * ROT + m;
    #pragma unroll
    for (int r = 0; r < 16; r++) {
        int qrow = (r & 3) + 8 * (r >> 2) + 4 * hl;
        float linv = 1.0f / __shfl(lsum, qrow);
        float* orow = ob + (size_t)qrow * (HEADS * ROT);
        #pragma unroll
        for (int dt = 0; dt < 4; dt++) orow[dt * 32] = oacc[dt][r] * linv;
    }
}

// ---------------------------------------------------------------------------
extern "C" void kernel_launch(void* const* d_in, const int* in_sizes, int n_in,
                              void* d_out, int out_size, void* d_ws, size_t ws_size,
                              hipStream_t stream) {
    (void)in_sizes; (void)n_in; (void)out_size; (void)ws_size;
    const float* x        = (const float*)d_in[0];
    const float* a        = (const float*)d_in[1];
    const float* Wq_x     = (const float*)d_in[2];
    const float* Wkv_x    = (const float*)d_in[3];
    const float* Wq_a     = (const float*)d_in[4];
    const float* Wkv_a    = (const float*)d_in[5];
    const float* qx_scale = (const float*)d_in[6];
    const float* qa_scale = (const float*)d_in[7];
    const float* kx_scale = (const float*)d_in[8];
    const float* ka_scale = (const float*)d_in[9];
    float* out = (float*)d_out;

    // ws: P fp32 (37.75MB) + qbuf bf16 (16MB) + kbuf/vbufT bf16 (1MB each)
    float* P = (float*)d_ws;
    unsigned short* qbuf  = (unsigned short*)(P + (size_t)2 * ROWS * PCOLS);
    unsigned short* kbuf  = qbuf + (size_t)BATCH * HEADS * SEQ * ROT;
    unsigned short* vbufT = kbuf + (size_t)BATCH * SEQ * ROT;

    gemm_kernel<<<dim3(32, 9, 2), 256, 0, stream>>>(x, a, Wq_x, Wkv_x, Wq_a, Wkv_a, P);
    fuse_kernel<<<dim3(ROWS), 256, 0, stream>>>(P, qx_scale, qa_scale, kx_scale, ka_scale,
                                                qbuf, kbuf, vbufT);
    attn_kernel<<<dim3(SEQ / 128, HEADS, BATCH), 256, 0, stream>>>(qbuf, kbuf, vbufT, out);
}

// Round 3
// 240.317 us; speedup vs baseline: 10.2840x; 1.9569x over previous
//
#include <hip/hip_runtime.h>
#include <math.h>

#define DIM   1024
#define HEADS 16
#define DH    64
#define ROT   128
#define BATCH 2
#define SEQ   2048
#define ROWS  (BATCH*SEQ)        // 4096
#define PCOLS (DIM + 2*DH)       // 1152 = [q(1024) | k(64) | v(64)] per side
#define ASCALE 0.08838834764831845f   // 1/sqrt(128), folded into qbuf

typedef short bf16x8 __attribute__((ext_vector_type(8)));
typedef float f32x16 __attribute__((ext_vector_type(16)));

static __device__ __forceinline__ unsigned short f2bf(float f) {
    union { float f; unsigned u; } v; v.f = f;
    unsigned r = v.u + 0x7fffu + ((v.u >> 16) & 1u);   // RNE (no NaN inputs here)
    return (unsigned short)(r >> 16);
}
static __device__ __forceinline__ float bf2f(unsigned short u) {
    union { unsigned u; float f; } v; v.u = (unsigned)u << 16;
    return v.f;
}

#define GL2LDS(gp, lp) __builtin_amdgcn_global_load_lds(                    \
    (const __attribute__((address_space(1))) void*)(gp),                    \
    (__attribute__((address_space(3))) void*)(lp), 16, 0, 0)

// ---------------------------------------------------------------------------
// Convert fp32 inputs -> bf16 staging buffers.
// xbf[2][4096][1024]  (x then a), wbf[2][1152][1024] ([Wq;Wkv] per side)
// Segment sizes all divisible by 1024 float4s -> no block straddles.
// ---------------------------------------------------------------------------
__global__ __launch_bounds__(256) void convert_kernel(
    const float* __restrict__ x, const float* __restrict__ a,
    const float* __restrict__ Wq_x, const float* __restrict__ Wkv_x,
    const float* __restrict__ Wq_a, const float* __restrict__ Wkv_a,
    unsigned short* __restrict__ xbf, unsigned short* __restrict__ wbf)
{
    const int blk = blockIdx.x;
    const float* s; unsigned short* d; int seg0;
    if      (blk < 1024) { s = x;     d = xbf;           seg0 = 0;    }
    else if (blk < 2048) { s = a;     d = xbf + 4194304; seg0 = 1024; }
    else if (blk < 2304) { s = Wq_x;  d = wbf;           seg0 = 2048; }
    else if (blk < 2336) { s = Wkv_x; d = wbf + 1048576; seg0 = 2304; }
    else if (blk < 2592) { s = Wq_a;  d = wbf + 1179648; seg0 = 2336; }
    else                 { s = Wkv_a; d = wbf + 2228224; seg0 = 2592; }
    long lb = ((long)blk - seg0) * 1024;
    #pragma unroll
    for (int j = 0; j < 4; j++) {
        long idx = lb + j * 256 + threadIdx.x;
        float4 v = ((const float4*)s)[idx];
        ((ushort4*)d)[idx] = make_ushort4(f2bf(v.x), f2bf(v.y), f2bf(v.z), f2bf(v.w));
    }
}

// ---------------------------------------------------------------------------
// MFMA GEMM (bf16, 32x32x16): P[side][row][col] = X[row,:].W[col,:], bf16 out.
// 128x128 tile, BK=32, 4 waves each 64x64 (2x2 MFMA tiles).
// global_load_lds width-16 staging; XOR-granule swizzle g^=(row>>1)&3 gives
// conflict-free ds_read_b128 (all 32 banks covered every 8 rows).
// ---------------------------------------------------------------------------
__global__ __launch_bounds__(256) void mfma_gemm_kernel(
    const unsigned short* __restrict__ xbf, const unsigned short* __restrict__ wbf,
    unsigned short* __restrict__ Pbf)
{
    const int mt = blockIdx.x, jt = blockIdx.y, side = blockIdx.z;
    const unsigned short* Ag = xbf + ((size_t)side * ROWS  + mt * 128) * DIM;
    const unsigned short* Bg = wbf + ((size_t)side * PCOLS + jt * 128) * DIM;
    unsigned short* Pp = Pbf + (size_t)side * ROWS * PCOLS;

    __shared__ __align__(16) unsigned short As[128 * 32];
    __shared__ __align__(16) unsigned short Bs[128 * 32];

    const int tid  = threadIdx.x;
    const int wave = tid >> 6, lane = tid & 63;
    const int m = lane & 31, hl = lane >> 5;
    const int wr = wave >> 1, wc = wave & 1;

    f32x16 acc[2][2];
    #pragma unroll
    for (int i2 = 0; i2 < 2; i2++)
        #pragma unroll
        for (int j2 = 0; j2 < 2; j2++) acc[i2][j2] = 0.0f;

    // staging slot for this thread (two per array): s = it*256+tid
    int sr[2], sg[2]; unsigned ldsb[2];
    #pragma unroll
    for (int it = 0; it < 2; it++) {
        int s = it * 256 + tid;
        sr[it] = s >> 2;
        sg[it] = (s & 3) ^ ((sr[it] >> 1) & 3);
        ldsb[it] = (unsigned)(it * 256 + wave * 64) * 16;   // bytes, wave-uniform
    }

    for (int k0 = 0; k0 < DIM; k0 += 32) {
        __syncthreads();
        #pragma unroll
        for (int it = 0; it < 2; it++) {
            GL2LDS(Ag + (size_t)sr[it] * DIM + k0 + sg[it] * 8, (char*)As + ldsb[it]);
            GL2LDS(Bg + (size_t)sr[it] * DIM + k0 + sg[it] * 8, (char*)Bs + ldsb[it]);
        }
        __syncthreads();
        #pragma unroll
        for (int kp = 0; kp < 2; kp++) {
            bf16x8 af[2], bff[2];
            #pragma unroll
            for (int t2 = 0; t2 < 2; t2++) {
                int ra = wr * 64 + t2 * 32 + m;
                int ga = (kp * 2 + hl) ^ ((ra >> 1) & 3);
                af[t2] = *(const bf16x8*)&As[ra * 32 + ga * 8];
                int rb = wc * 64 + t2 * 32 + m;
                int gb = (kp * 2 + hl) ^ ((rb >> 1) & 3);
                bff[t2] = *(const bf16x8*)&Bs[rb * 32 + gb * 8];
            }
            #pragma unroll
            for (int i2 = 0; i2 < 2; i2++)
                #pragma unroll
                for (int j2 = 0; j2 < 2; j2++)
                    acc[i2][j2] = __builtin_amdgcn_mfma_f32_32x32x16_bf16(
                        af[i2], bff[j2], acc[i2][j2], 0, 0, 0);
        }
    }

    const int m0 = mt * 128 + wr * 64;
    const int n0 = jt * 128 + wc * 64;
    #pragma unroll
    for (int i2 = 0; i2 < 2; i2++)
        #pragma unroll
        for (int j2 = 0; j2 < 2; j2++)
            #pragma unroll
            for (int r = 0; r < 16; r++) {
                int row = m0 + i2 * 32 + (r & 3) + 8 * (r >> 2) + 4 * hl;
                int col = n0 + j2 * 32 + m;
                Pp[(size_t)row * PCOLS + col] = f2bf(acc[i2][j2][r]);
            }
}

// ---------------------------------------------------------------------------
// Fuse: l2norm + scale + concat + rotary (reads bf16 P).
// Outputs (bf16): qbuf[b][h][n][128] (pre-scaled by 1/sqrt(128)),
//                 kbuf[b][n][128], vbufT[b][128][n]
// ---------------------------------------------------------------------------
__global__ __launch_bounds__(256) void fuse_kernel(
    const unsigned short* __restrict__ Pbf,
    const float* __restrict__ qx_scale, const float* __restrict__ qa_scale,
    const float* __restrict__ kx_scale, const float* __restrict__ ka_scale,
    unsigned short* __restrict__ qbuf, unsigned short* __restrict__ kbuf,
    unsigned short* __restrict__ vbufT)
{
    const int row = blockIdx.x;            // b*SEQ + pos
    const int b = row >> 11, pos = row & 2047;
    const unsigned short* Px = Pbf + (size_t)row * PCOLS;
    const unsigned short* Pa = Pbf + (size_t)ROWS * PCOLS + (size_t)row * PCOLS;
    const int tid = threadIdx.x;
    const int h = tid >> 4, i = tid & 15;
    const float fpos = (float)pos;
    const float LN1E4_64 = 0.14391156831213f;   // ln(10000)/64

    // ---- Q ----
    ushort4 xu = *(const ushort4*)(Px + h * DH + i * 4);
    ushort4 au = *(const ushort4*)(Pa + h * DH + i * 4);
    float xr[4] = {bf2f(xu.x), bf2f(xu.y), bf2f(xu.z), bf2f(xu.w)};
    float ar[4] = {bf2f(au.x), bf2f(au.y), bf2f(au.z), bf2f(au.w)};
    float ssx = xr[0]*xr[0] + xr[1]*xr[1] + xr[2]*xr[2] + xr[3]*xr[3];
    float ssa = ar[0]*ar[0] + ar[1]*ar[1] + ar[2]*ar[2] + ar[3]*ar[3];
    #pragma unroll
    for (int off = 1; off < 16; off <<= 1) {
        ssx += __shfl_xor(ssx, off, 16);
        ssa += __shfl_xor(ssa, off, 16);
    }
    float inx = 1.0f / fmaxf(sqrtf(ssx), 1e-12f);
    float ina = 1.0f / fmaxf(sqrtf(ssa), 1e-12f);
    unsigned short qlo[4], qhi[4];
    #pragma unroll
    for (int j = 0; j < 4; j++) {
        int jd = i * 4 + j;
        float qx = xr[j] * inx * qx_scale[h * DH + jd];
        float qa = ar[j] * ina * qa_scale[h * DH + jd];
        float th = fpos * expf(-LN1E4_64 * (float)jd);
        float sn, cs; sincosf(th, &sn, &cs);
        qlo[j] = f2bf((qx * cs - qa * sn) * ASCALE);
        qhi[j] = f2bf((qa * cs + qx * sn) * ASCALE);
    }
    unsigned short* qp = qbuf + (((size_t)(b * HEADS + h)) * SEQ + pos) * ROT;
    *(ushort4*)(qp + i * 4)      = make_ushort4(qlo[0], qlo[1], qlo[2], qlo[3]);
    *(ushort4*)(qp + DH + i * 4) = make_ushort4(qhi[0], qhi[1], qhi[2], qhi[3]);

    // ---- K ----
    if (tid < 16) {
        ushort4 kxu = *(const ushort4*)(Px + DIM + tid * 4);
        ushort4 kau = *(const ushort4*)(Pa + DIM + tid * 4);
        float kxr[4] = {bf2f(kxu.x), bf2f(kxu.y), bf2f(kxu.z), bf2f(kxu.w)};
        float kar[4] = {bf2f(kau.x), bf2f(kau.y), bf2f(kau.z), bf2f(kau.w)};
        float sx = kxr[0]*kxr[0] + kxr[1]*kxr[1] + kxr[2]*kxr[2] + kxr[3]*kxr[3];
        float sa = kar[0]*kar[0] + kar[1]*kar[1] + kar[2]*kar[2] + kar[3]*kar[3];
        #pragma unroll
        for (int off = 1; off < 16; off <<= 1) {
            sx += __shfl_xor(sx, off, 16);
            sa += __shfl_xor(sa, off, 16);
        }
        float ikx = 1.0f / fmaxf(sqrtf(sx), 1e-12f);
        float ika = 1.0f / fmaxf(sqrtf(sa), 1e-12f);
        unsigned short klo[4], khi[4];
        #pragma unroll
        for (int j = 0; j < 4; j++) {
            int jd = tid * 4 + j;
            float kx = kxr[j] * ikx * kx_scale[jd];
            float ka = kar[j] * ika * ka_scale[jd];
            float th = fpos * expf(-LN1E4_64 * (float)jd);
            float sn, cs; sincosf(th, &sn, &cs);
            klo[j] = f2bf(kx * cs - ka * sn);
            khi[j] = f2bf(ka * cs + kx * sn);
        }
        unsigned short* kp = kbuf + ((size_t)b * SEQ + pos) * ROT;
        *(ushort4*)(kp + tid * 4)      = make_ushort4(klo[0], klo[1], klo[2], klo[3]);
        *(ushort4*)(kp + DH + tid * 4) = make_ushort4(khi[0], khi[1], khi[2], khi[3]);
    }
    // ---- V (transposed store, exact bf16 copy) ----
    if (tid >= 64 && tid < 96) {
        int iv = tid - 64;
        unsigned short* vT = vbufT + (size_t)b * ROT * SEQ + pos;
        const unsigned short* src; int d;
        if (iv < 16) { src = Px + DIM + DH + iv * 4;        d = iv * 4;              }
        else         { src = Pa + DIM + DH + (iv - 16) * 4; d = DH + (iv - 16) * 4;  }
        ushort4 v4 = *(const ushort4*)src;
        vT[(size_t)(d + 0) * SEQ] = v4.x;
        vT[(size_t)(d + 1) * SEQ] = v4.y;
        vT[(size_t)(d + 2) * SEQ] = v4.z;
        vT[(size_t)(d + 3) * SEQ] = v4.w;
    }
}

// ---------------------------------------------------------------------------
// MFMA flash attention (bf16, 32x32x16) — unchanged from R1.
// ---------------------------------------------------------------------------
__global__ __launch_bounds__(256, 2) void attn_kernel(
    const unsigned short* __restrict__ qbuf,
    const unsigned short* __restrict__ kbuf,
    const unsigned short* __restrict__ vbufT,
    float* __restrict__ out)
{
    const int qb = blockIdx.x, h = blockIdx.y, b = blockIdx.z;
    __shared__ __align__(16) unsigned short Ks[64 * 128];
    __shared__ __align__(16) unsigned short Vs[128 * 64];
    const int tid  = threadIdx.x;
    const int wave = tid >> 6, lane = tid & 63;
    const int m = lane & 31, hl = lane >> 5;
    const int q0 = qb * 128 + wave * 32;

    bf16x8 qf[8];
    {
        const unsigned short* qp = qbuf + (((size_t)(b * HEADS + h)) * SEQ + q0 + m) * ROT + hl * 8;
        #pragma unroll
        for (int c = 0; c < 8; c++) qf[c] = *(const bf16x8*)(qp + c * 16);
    }

    f32x16 oacc[4];
    #pragma unroll
    for (int dt = 0; dt < 4; dt++) oacc[dt] = 0.0f;
    float lsum = 0.f;

    const unsigned short* kb_ = kbuf  + (size_t)b * SEQ * ROT;
    const unsigned short* vb_ = vbufT + (size_t)b * ROT * SEQ;

    for (int t = 0; t < SEQ / 64; t++) {
        __syncthreads();
        #pragma unroll
        for (int i = 0; i < 4; i++) {
            int fg = i * 256 + tid;
            int row = fg >> 4, gi = fg & 15;            // K: 64 rows x 16 granules
            uint4 val = *(const uint4*)(kb_ + (size_t)(t * 64 + row) * ROT + gi * 8);
            *(uint4*)&Ks[row * 128 + ((gi ^ (row & 15)) << 3)] = val;
            int rv = fg >> 3, gv = fg & 7;              // V^T: 128 rows x 8 granules
            uint4 vv = *(const uint4*)(vb_ + (size_t)rv * SEQ + t * 64 + gv * 8);
            *(uint4*)&Vs[rv * 64 + ((gv ^ (rv & 7)) << 3)] = vv;
        }
        __syncthreads();

        #pragma unroll
        for (int kg = 0; kg < 2; kg++) {
            f32x16 st = 0.0f;
            #pragma unroll
            for (int c = 0; c < 8; c++) {
                bf16x8 af = *(const bf16x8*)&Ks[(kg * 32 + m) * 128 + (((2 * c + hl) ^ (m & 15)) << 3)];
                st = __builtin_amdgcn_mfma_f32_32x32x16_bf16(af, qf[c], st, 0, 0, 0);
            }
            float p[16];
            #pragma unroll
            for (int r = 0; r < 16; r++) { p[r] = __expf(st[r]); lsum += p[r]; }

            #pragma unroll
            for (int w = 0; w < 2; w++) {
                float pj[8];
                #pragma unroll
                for (int tq = 0; tq < 4; tq++) {
                    float send = hl ? p[8 * w + tq]     : p[8 * w + 4 + tq];
                    float own  = hl ? p[8 * w + 4 + tq] : p[8 * w + tq];
                    float recv = __shfl_xor(send, 32);
                    pj[tq]     = hl ? recv : own;
                    pj[4 + tq] = hl ? own  : recv;
                }
                bf16x8 aP;
                #pragma unroll
                for (int j = 0; j < 8; j++) aP[j] = (short)f2bf(pj[j]);
                #pragma unroll
                for (int dt = 0; dt < 4; dt++) {
                    bf16x8 vf = *(const bf16x8*)&Vs[(dt * 32 + m) * 64 +
                                                    (((kg * 4 + w * 2 + hl) ^ (m & 7)) << 3)];
                    oacc[dt] = __builtin_amdgcn_mfma_f32_32x32x16_bf16(aP, vf, oacc[dt], 0, 0, 0);
                }
            }
        }
    }

    lsum += __shfl_xor(lsum, 32);
    float* ob = out + ((size_t)(b * SEQ + q0)) * (HEADS * ROT) + h * ROT + m;
    #pragma unroll
    for (int r = 0; r < 16; r++) {
        int qrow = (r & 3) + 8 * (r >> 2) + 4 * hl;
        float linv = 1.0f / __shfl(lsum, qrow);
        float* orow = ob + (size_t)qrow * (HEADS * ROT);
        #pragma unroll
        for (int dt = 0; dt < 4; dt++) orow[dt * 32] = oacc[dt][r] * linv;
    }
}

// ---------------------------------------------------------------------------
extern "C" void kernel_launch(void* const* d_in, const int* in_sizes, int n_in,
                              void* d_out, int out_size, void* d_ws, size_t ws_size,
                              hipStream_t stream) {
    (void)in_sizes; (void)n_in; (void)out_size; (void)ws_size;
    const float* x        = (const float*)d_in[0];
    const float* a        = (const float*)d_in[1];
    const float* Wq_x     = (const float*)d_in[2];
    const float* Wkv_x    = (const float*)d_in[3];
    const float* Wq_a     = (const float*)d_in[4];
    const float* Wkv_a    = (const float*)d_in[5];
    const float* qx_scale = (const float*)d_in[6];
    const float* qa_scale = (const float*)d_in[7];
    const float* kx_scale = (const float*)d_in[8];
    const float* ka_scale = (const float*)d_in[9];
    float* out = (float*)d_out;

    // ws (bf16 elements): Pbf 9.44M | qbuf 8.39M | kbuf 0.52M | vbufT 0.52M
    //                     | xbf 8.39M | wbf 2.36M  => 59.2 MB total
    unsigned short* Pbf   = (unsigned short*)d_ws;
    unsigned short* qbuf  = Pbf   + (size_t)2 * ROWS * PCOLS;
    unsigned short* kbuf  = qbuf  + (size_t)BATCH * HEADS * SEQ * ROT;
    unsigned short* vbufT = kbuf  + (size_t)BATCH * SEQ * ROT;
    unsigned short* xbf   = vbufT + (size_t)BATCH * SEQ * ROT;
    unsigned short* wbf   = xbf   + (size_t)2 * ROWS * DIM;

    convert_kernel<<<dim3(2624), 256, 0, stream>>>(x, a, Wq_x, Wkv_x, Wq_a, Wkv_a, xbf, wbf);
    mfma_gemm_kernel<<<dim3(32, 9, 2), 256, 0, stream>>>(xbf, wbf, Pbf);
    fuse_kernel<<<dim3(ROWS), 256, 0, stream>>>(Pbf, qx_scale, qa_scale, kx_scale, ka_scale,
                                                qbuf, kbuf, vbufT);
    attn_kernel<<<dim3(SEQ / 128, HEADS, BATCH), 256, 0, stream>>>(qbuf, kbuf, vbufT, out);
}